// Round 9
// baseline (3345.430 us; speedup 1.0000x reference)
//
#include <hip/hip_runtime.h>
#include <math.h>

#define BATCH 10
#define HID 128
#define OUT 7
#define MAXLEN 2048
#define NG (4*HID)          // 512 gates
#define NT 1024             // threads: 2 per gate (k-split halves)
#define WOUT_STRIDE 132     // pad 128 -> 132 to avoid LDS bank conflicts

__device__ __forceinline__ float sigmoidf_(float x) { return 1.0f / (1.0f + expf(-x)); }

// AGPR -> VGPR move (the only legal path: gfx950 VALU can't take AGPR srcs,
// proven by R8's assembler rejection). Constraint-based (compiler-allocated
// AGPR), fake dep on the h component blocks LICM from hoisting 64 reads.
#define AR1(T, W, DEP) asm("v_accvgpr_read_b32 %0, %1" : "=v"(T) : "a"(W), "v"(DEP))

__global__
__attribute__((amdgpu_flat_work_group_size(NT, NT), amdgpu_waves_per_eu(4, 4)))
void decoder_rnn_kernel(const float* __restrict__ h0,
                        const float* __restrict__ c0,
                        const float* __restrict__ tonehot,   // (MAXLEN+1, 1, OUT)
                        const void*  __restrict__ tf_raw,    // bool mask, int8 or int32
                        const float* __restrict__ Wih,       // (4H, OUT)
                        const float* __restrict__ Whh,       // (4H, H)
                        const float* __restrict__ bih,
                        const float* __restrict__ bhh,
                        const float* __restrict__ Wout,      // (OUT, H)
                        const float* __restrict__ bout,
                        float* __restrict__ out)
{
    __shared__ __align__(16) float h_lds[HID];
    __shared__ float partA_lds[NG];              // half0 partial (incl. bias)
    __shared__ float partB_lds[NG];              // half1 partial
    __shared__ float Wih_lds[OUT * NG];          // transposed: [x][g]
    __shared__ float Wout_lds[OUT * WOUT_STRIDE];
    __shared__ float bout_lds[8];
    __shared__ int   tgt_lds[MAXLEN];
    __shared__ unsigned char tf_lds[MAXLEN];
    __shared__ int   xsel_sh;
    __shared__ int   tf_byte_mode;

    const int t    = threadIdx.x;     // 0..1023
    const int g    = t & (NG - 1);    // gate index 0..511
    const int half = t >> 9;          // k-half: 0 -> k 0..63, 1 -> k 64..127
    const int b    = blockIdx.x;      // batch chain

    // ---- half-row of W_hh into 64 AGPRs (one-time "+a" pin; R6/R7 proved
    //      this config stays resident: VGPR 64 + AGPR 64 = 128 budget) ----
    float wf[64];
    {
        const float4* wr = (const float4*)(Whh + (size_t)g * HID + half * 64);
        #pragma unroll
        for (int i = 0; i < 16; i++) {
            float4 v = wr[i];
            wf[4*i+0] = v.x; wf[4*i+1] = v.y; wf[4*i+2] = v.z; wf[4*i+3] = v.w;
        }
    }
#define PINA8(i) asm volatile("" : "+a"(wf[i]), "+a"(wf[i+1]), "+a"(wf[i+2]), "+a"(wf[i+3]), \
                                   "+a"(wf[i+4]), "+a"(wf[i+5]), "+a"(wf[i+6]), "+a"(wf[i+7]))
    PINA8(0); PINA8(8); PINA8(16); PINA8(24);
    PINA8(32); PINA8(40); PINA8(48); PINA8(56);
#undef PINA8

    const float bias_g = (half == 0) ? (bih[g] + bhh[g]) : 0.0f;

    // ---- W_ih transposed into LDS: Wih_lds[x*NG + gg] ----
    for (int idx = t; idx < OUT * NG; idx += NT) {
        int x = idx >> 9, gg = idx & (NG - 1);
        Wih_lds[x * NG + gg] = Wih[gg * OUT + x];
    }

    // ---- W_out into LDS with padded stride ----
    for (int idx = t; idx < OUT * HID; idx += NT) {
        int j = idx / HID, k = idx % HID;
        Wout_lds[j * WOUT_STRIDE + k] = Wout[idx];
    }
    if (t < 8) bout_lds[t] = (t < OUT) ? bout[t] : 0.0f;

    // ---- target indices: tgt_next[s] = argmax(onehot[s+1]) ----
    for (int s = t; s < MAXLEN; s += NT) {
        const float* row = tonehot + (size_t)(s + 1) * OUT;
        int idx = 0;
        #pragma unroll
        for (int j = 0; j < OUT; j++) if (row[j] > 0.5f) idx = j;
        tgt_lds[s] = idx;
    }

    // ---- tf_mask layout detection (int8 bool vs int32) ----
    if (t == 0) { tf_byte_mode = 0; xsel_sh = OUT - 1; }  // x0 = one-hot at OUT-1
    __syncthreads();
    {
        const unsigned char* tb = (const unsigned char*)tf_raw;
        int mis = 0;
        for (int p = t; p < MAXLEN; p += NT)          // first 2048 bytes: safe in both layouts
            if ((p & 3) && tb[p]) mis = 1;
        if (mis) atomicOr(&tf_byte_mode, 1);
    }
    // ---- state init ----
    if (t < HID) h_lds[t] = h0[b * HID + t];
    float c_reg = (t < HID) ? c0[b * HID + t] : 0.0f;
    __syncthreads();
    if (tf_byte_mode) {
        const unsigned char* tb = (const unsigned char*)tf_raw;
        for (int s = t; s < MAXLEN; s += NT) tf_lds[s] = (tb[s] != 0);
    } else {
        const int* ti = (const int*)tf_raw;
        for (int s = t; s < MAXLEN; s += NT) tf_lds[s] = (ti[s] != 0);
    }
    __syncthreads();   // setup LDS (incl. Wout/bout) + h0 ready

    // ---- wave 0: cache W_out row-slice + bias in registers ----
    float woutr[16];
    float boutr = 0.0f;
    const int j_cls = t & 7;        // output class (7 is a dummy)
    const int seg   = t >> 3;       // k-segment (16 wide), valid for t<64
    if (t < 64) {
        #pragma unroll
        for (int kk = 0; kk < 16; kk++)
            woutr[kk] = Wout_lds[j_cls * WOUT_STRIDE + seg * 16 + kk];
        boutr = bout_lds[j_cls];
    } else {
        #pragma unroll
        for (int kk = 0; kk < 16; kk++) woutr[kk] = 0.0f;
    }

    float* outlp = out + (size_t)b * MAXLEN * OUT;

    for (int s = 0; s < MAXLEN; s++) {
        // entry invariant: h_lds = h_s (h2 of step s-1), barrier done.

        // ---- gate half-dot: ds_read_b128 broadcast h × AGPR weights ----
        // 2 VALU instr/MAC (accvgpr_read + fma); LDS reads overlap on DS pipe.
        const float4* h4 = (const float4*)h_lds + (half << 4);
        float ac0 = 0.f, ac1 = 0.f, ac2 = 0.f, ac3 = 0.f;
        #pragma unroll
        for (int i = 0; i < 16; i++) {
            float4 hv = h4[i];              // all lanes same address: broadcast
            float w0, w1, w2, w3;
            AR1(w0, wf[4*i+0], hv.x);
            AR1(w1, wf[4*i+1], hv.y);
            AR1(w2, wf[4*i+2], hv.z);
            AR1(w3, wf[4*i+3], hv.w);
            ac0 = fmaf(hv.x, w0, ac0);
            ac1 = fmaf(hv.y, w1, ac1);
            ac2 = fmaf(hv.z, w2, ac2);
            ac3 = fmaf(hv.w, w3, ac3);
        }
        float acc = (ac0 + ac1) + (ac2 + ac3);
        if (half) partB_lds[g] = acc;
        else      partA_lds[g] = acc + bias_g;

        // ---- wave 0 concurrently: logits for step s-1, xsel for step s ----
        if (s > 0 && t < 64) {
            const float4* hh4 = (const float4*)h_lds;
            float p = 0.f;
            #pragma unroll
            for (int q = 0; q < 4; q++) {
                float4 hv = hh4[seg * 4 + q];
                p += hv.x * woutr[4*q+0];
                p += hv.y * woutr[4*q+1];
                p += hv.z * woutr[4*q+2];
                p += hv.w * woutr[4*q+3];
            }
            p += __shfl_xor(p, 8, 64);
            p += __shfl_xor(p, 16, 64);
            p += __shfl_xor(p, 32, 64);
            float logit = (j_cls < OUT) ? (p + boutr) : -INFINITY;

            float mv = logit; int mi = j_cls;
            #pragma unroll
            for (int d = 1; d < 8; d <<= 1) {
                float ov = __shfl_xor(mv, d, 64);
                int   oi = __shfl_xor(mi, d, 64);
                if (ov > mv || (ov == mv && oi < mi)) { mv = ov; mi = oi; }
            }
            float e = (j_cls < OUT) ? expf(logit - mv) : 0.0f;
            float ssum = e;
            #pragma unroll
            for (int d = 1; d < 8; d <<= 1) ssum += __shfl_xor(ssum, d, 64);
            float lse = mv + logf(ssum);
            if (t < OUT) outlp[(s - 1) * OUT + t] = logit - lse;
            if (t == 0)  xsel_sh = tf_lds[s - 1] ? tgt_lds[s - 1] : mi;
        }
        __syncthreads();   // A: partials + xsel ready

        // ---- pointwise: combine halves + Wih column + all activations ----
        if (t < HID) {
            const int xoff = xsel_sh * NG;
            float ri = partA_lds[t]         + partB_lds[t]         + Wih_lds[xoff + t];
            float rf = partA_lds[HID + t]   + partB_lds[HID + t]   + Wih_lds[xoff + HID + t];
            float rg = partA_lds[2*HID + t] + partB_lds[2*HID + t] + Wih_lds[xoff + 2*HID + t];
            float ro = partA_lds[3*HID + t] + partB_lds[3*HID + t] + Wih_lds[xoff + 3*HID + t];
            float c2 = sigmoidf_(rf) * c_reg + sigmoidf_(ri) * tanhf(rg);
            c_reg = c2;
            h_lds[t] = sigmoidf_(ro) * tanhf(c2);
        }
        __syncthreads();   // C: h2 ready
    }

    // ---- epilogue: logits for final step ----
    if (t < 64) {
        const float4* hh4 = (const float4*)h_lds;
        float p = 0.f;
        #pragma unroll
        for (int q = 0; q < 4; q++) {
            float4 hv = hh4[seg * 4 + q];
            p += hv.x * woutr[4*q+0];
            p += hv.y * woutr[4*q+1];
            p += hv.z * woutr[4*q+2];
            p += hv.w * woutr[4*q+3];
        }
        p += __shfl_xor(p, 8, 64);
        p += __shfl_xor(p, 16, 64);
        p += __shfl_xor(p, 32, 64);
        float logit = (j_cls < OUT) ? (p + boutr) : -INFINITY;
        float mv = logit;
        #pragma unroll
        for (int d = 1; d < 8; d <<= 1) {
            float ov = __shfl_xor(mv, d, 64);
            if (ov > mv) mv = ov;
        }
        float e = (j_cls < OUT) ? expf(logit - mv) : 0.0f;
        float ssum = e;
        #pragma unroll
        for (int d = 1; d < 8; d <<= 1) ssum += __shfl_xor(ssum, d, 64);
        float lse = mv + logf(ssum);
        if (t < OUT) outlp[(MAXLEN - 1) * OUT + t] = logit - lse;
    }

    if (t < HID) {
        out[(size_t)BATCH * MAXLEN * OUT + b * HID + t] = h_lds[t];                 // hT
        out[(size_t)BATCH * MAXLEN * OUT + BATCH * HID + b * HID + t] = c_reg;      // cT
    }
}

extern "C" void kernel_launch(void* const* d_in, const int* in_sizes, int n_in,
                              void* d_out, int out_size, void* d_ws, size_t ws_size,
                              hipStream_t stream) {
    const float* h0    = (const float*)d_in[0];
    const float* c0    = (const float*)d_in[1];
    const float* toh   = (const float*)d_in[2];
    const void*  tfm   = (const void*) d_in[3];
    const float* Wih   = (const float*)d_in[4];
    const float* Whh   = (const float*)d_in[5];
    const float* bih   = (const float*)d_in[6];
    const float* bhh   = (const float*)d_in[7];
    const float* Wout  = (const float*)d_in[8];
    const float* bout  = (const float*)d_in[9];
    float* out = (float*)d_out;

    decoder_rnn_kernel<<<dim3(BATCH), dim3(NT), 0, stream>>>(
        h0, c0, toh, tfm, Wih, Whh, bih, bhh, Wout, bout, out);
}

// Round 10
// 3091.601 us; speedup vs baseline: 1.0821x; 1.0821x over previous
//
#include <hip/hip_runtime.h>
#include <math.h>

#define BATCH 10
#define HID 128
#define OUT 7
#define MAXLEN 2048
#define NG (4*HID)          // 512 gates
#define NT 1024             // threads: 2 per gate (k-split halves)
#define WOUT_STRIDE 132     // pad 128 -> 132 to avoid LDS bank conflicts
#define LOGBUF 256          // log-prob staging depth (flush every 256 steps)

__device__ __forceinline__ float sigmoidf_(float x) { return 1.0f / (1.0f + expf(-x)); }

__global__
__attribute__((amdgpu_flat_work_group_size(NT, NT), amdgpu_waves_per_eu(4, 4)))
void decoder_rnn_kernel(const float* __restrict__ h0,
                        const float* __restrict__ c0,
                        const float* __restrict__ tonehot,   // (MAXLEN+1, 1, OUT)
                        const void*  __restrict__ tf_raw,    // bool mask, int8 or int32
                        const float* __restrict__ Wih,       // (4H, OUT)
                        const float* __restrict__ Whh,       // (4H, H)
                        const float* __restrict__ bih,
                        const float* __restrict__ bhh,
                        const float* __restrict__ Wout,      // (OUT, H)
                        const float* __restrict__ bout,
                        float* __restrict__ out)
{
    __shared__ __align__(16) float h_lds[HID];
    __shared__ float part_lds[NG];               // half1 partial dots
    __shared__ float gates_lds[NG];              // transformed gates
    __shared__ float Wih_lds[OUT * NG];          // transposed: [x][g]
    __shared__ float Wout_lds[OUT * WOUT_STRIDE];
    __shared__ float bout_lds[8];
    __shared__ float log_lds[LOGBUF][OUT];       // staged log-probs (no per-step HBM store!)
    __shared__ int   tgt_lds[MAXLEN];
    __shared__ unsigned char tf_lds[MAXLEN];
    __shared__ int   xsel_sh;
    __shared__ int   tf_byte_mode;

    const int t    = threadIdx.x;     // 0..1023
    const int g    = t & (NG - 1);    // gate index 0..511
    const int half = t >> 9;          // k-half: 0 -> k 0..63, 1 -> k 64..127
    const int lane = t & 63;
    const int b    = blockIdx.x;      // batch chain

    // ---- half-row of W_hh into 64 registers; single opaque pin ----
    // (R6/R7-proven: allocator parks these in AGPRs, reload = 1 accvgpr_read)
    float wf[64];
    {
        const float4* wr = (const float4*)(Whh + (size_t)g * HID + half * 64);
        #pragma unroll
        for (int i = 0; i < 16; i++) {
            float4 v = wr[i];
            wf[4*i+0] = v.x; wf[4*i+1] = v.y; wf[4*i+2] = v.z; wf[4*i+3] = v.w;
        }
    }
#define PIN8(i) asm volatile("" : "+v"(wf[i]), "+v"(wf[i+1]), "+v"(wf[i+2]), "+v"(wf[i+3]), \
                                  "+v"(wf[i+4]), "+v"(wf[i+5]), "+v"(wf[i+6]), "+v"(wf[i+7]))
    PIN8(0); PIN8(8); PIN8(16); PIN8(24);
    PIN8(32); PIN8(40); PIN8(48); PIN8(56);
#undef PIN8

    const float bias_g   = (half == 0) ? (bih[g] + bhh[g]) : 0.0f;
    const bool  is_gcell = ((g >> 7) == 2);      // gates 256..383 use tanh

    // ---- W_ih transposed into LDS: Wih_lds[x*NG + gg] ----
    for (int idx = t; idx < OUT * NG; idx += NT) {
        int x = idx >> 9, gg = idx & (NG - 1);
        Wih_lds[x * NG + gg] = Wih[gg * OUT + x];
    }

    // ---- W_out into LDS with padded stride ----
    for (int idx = t; idx < OUT * HID; idx += NT) {
        int j = idx / HID, k = idx % HID;
        Wout_lds[j * WOUT_STRIDE + k] = Wout[idx];
    }
    if (t < 8) bout_lds[t] = (t < OUT) ? bout[t] : 0.0f;

    // ---- target indices: tgt_next[s] = argmax(onehot[s+1]) ----
    for (int s = t; s < MAXLEN; s += NT) {
        const float* row = tonehot + (size_t)(s + 1) * OUT;
        int idx = 0;
        #pragma unroll
        for (int j = 0; j < OUT; j++) if (row[j] > 0.5f) idx = j;
        tgt_lds[s] = idx;
    }

    // ---- tf_mask layout detection (int8 bool vs int32) ----
    if (t == 0) { tf_byte_mode = 0; xsel_sh = OUT - 1; }  // x0 = one-hot at OUT-1
    __syncthreads();
    {
        const unsigned char* tb = (const unsigned char*)tf_raw;
        int mis = 0;
        for (int p = t; p < MAXLEN; p += NT)          // first 2048 bytes: safe in both layouts
            if ((p & 3) && tb[p]) mis = 1;
        if (mis) atomicOr(&tf_byte_mode, 1);
    }
    // ---- state init ----
    if (t < HID) h_lds[t] = h0[b * HID + t];
    float c_reg = (t < HID) ? c0[b * HID + t] : 0.0f;
    __syncthreads();
    if (tf_byte_mode) {
        const unsigned char* tb = (const unsigned char*)tf_raw;
        for (int s = t; s < MAXLEN; s += NT) tf_lds[s] = (tb[s] != 0);
    } else {
        const int* ti = (const int*)tf_raw;
        for (int s = t; s < MAXLEN; s += NT) tf_lds[s] = (ti[s] != 0);
    }
    __syncthreads();   // setup LDS (incl. Wout/bout) + h0 ready

    // ---- wave 0: cache W_out row-slice + bias in registers ----
    float woutr[16];
    float boutr = 0.0f;
    const int j_cls = t & 7;        // output class (7 is a dummy)
    const int seg   = t >> 3;       // k-segment (16 wide), valid for t<64
    if (t < 64) {
        #pragma unroll
        for (int kk = 0; kk < 16; kk++)
            woutr[kk] = Wout_lds[j_cls * WOUT_STRIDE + seg * 16 + kk];
        boutr = bout_lds[j_cls];
    } else {
        #pragma unroll
        for (int kk = 0; kk < 16; kk++) woutr[kk] = 0.0f;
    }

    float* outlp = out + (size_t)b * MAXLEN * OUT;

    for (int s = 0; s < MAXLEN; s++) {
        // entry invariant: h_lds = h_{s} input (== h2 of step s-1), barrier done.

        // ---- gate half-dot via readlane broadcast (all 16 waves) ----
        float hreg = h_lds[(half << 6) + lane];
        int   hi   = __float_as_int(hreg);
        float a0 = (half == 0) ? bias_g : 0.0f;
        float a1 = 0.f, a2 = 0.f, a3 = 0.f;
        #pragma unroll
        for (int j = 0; j < 64; j += 4) {
            float s0 = __int_as_float(__builtin_amdgcn_readlane(hi, j));
            float s1 = __int_as_float(__builtin_amdgcn_readlane(hi, j + 1));
            float s2 = __int_as_float(__builtin_amdgcn_readlane(hi, j + 2));
            float s3 = __int_as_float(__builtin_amdgcn_readlane(hi, j + 3));
            a0 += s0 * wf[j];
            a1 += s1 * wf[j + 1];
            a2 += s2 * wf[j + 2];
            a3 += s3 * wf[j + 3];
        }
        float acc = (a0 + a1) + (a2 + a3);
        if (half) part_lds[g] = acc;

        // ---- wave 0 concurrently: logits for step s-1, xsel for step s ----
        // Log-probs go to LDS ring buffer — NO per-step global store, so no
        // vmcnt/expcnt drain at the next barrier (the R1-R9 hidden constant).
        if (s > 0 && t < 64) {
            const float4* h4 = (const float4*)h_lds;
            float p = 0.f;
            #pragma unroll
            for (int q = 0; q < 4; q++) {
                float4 hv = h4[seg * 4 + q];
                p += hv.x * woutr[4*q+0];
                p += hv.y * woutr[4*q+1];
                p += hv.z * woutr[4*q+2];
                p += hv.w * woutr[4*q+3];
            }
            p += __shfl_xor(p, 8, 64);
            p += __shfl_xor(p, 16, 64);
            p += __shfl_xor(p, 32, 64);
            float logit = (j_cls < OUT) ? (p + boutr) : -INFINITY;

            float mv = logit; int mi = j_cls;
            #pragma unroll
            for (int d = 1; d < 8; d <<= 1) {
                float ov = __shfl_xor(mv, d, 64);
                int   oi = __shfl_xor(mi, d, 64);
                if (ov > mv || (ov == mv && oi < mi)) { mv = ov; mi = oi; }
            }
            float e = (j_cls < OUT) ? expf(logit - mv) : 0.0f;
            float ssum = e;
            #pragma unroll
            for (int d = 1; d < 8; d <<= 1) ssum += __shfl_xor(ssum, d, 64);
            float lse = mv + logf(ssum);
            if (t < OUT) log_lds[(s - 1) & (LOGBUF - 1)][t] = logit - lse;
            if (t == 0)  xsel_sh = tf_lds[s - 1] ? tgt_lds[s - 1] : mi;
        }
        __syncthreads();   // A: partials + xsel + log slot (s-1) ready

        // ---- bulk flush of staged log-probs (once per 256 steps) ----
        if ((s & (LOGBUF - 1)) == 0 && s > 0) {
            const int base = s - LOGBUF;      // steps base..base+255 in slots 0..255
            for (int i = t; i < LOGBUF * OUT; i += NT) {
                int st = i / OUT, j = i - st * OUT;
                outlp[(size_t)(base + st) * OUT + j] = log_lds[st][j];
            }   // fire-and-forget; drains at a later barrier, amortized 1/256
        }

        // ---- combine halves + transcendental (half0 threads own gate g) ----
        if (half == 0) {
            float raw = acc + part_lds[g] + Wih_lds[xsel_sh * NG + g];
            gates_lds[g] = is_gcell ? tanhf(raw) : sigmoidf_(raw);
        }
        __syncthreads();   // B: transformed gates ready

        // ---- LSTM combine (threads 0..127), c stays in register ----
        if (t < HID) {
            float ti_ = gates_lds[t];
            float tf_ = gates_lds[HID + t];
            float tg_ = gates_lds[2 * HID + t];
            float to_ = gates_lds[3 * HID + t];
            float c2 = tf_ * c_reg + ti_ * tg_;
            c_reg = c2;
            h_lds[t] = to_ * tanhf(c2);
        }
        __syncthreads();   // C: h2 ready
    }

    // ---- epilogue: logits for final step -> slot 255, then final flush ----
    if (t < 64) {
        const float4* h4 = (const float4*)h_lds;
        float p = 0.f;
        #pragma unroll
        for (int q = 0; q < 4; q++) {
            float4 hv = h4[seg * 4 + q];
            p += hv.x * woutr[4*q+0];
            p += hv.y * woutr[4*q+1];
            p += hv.z * woutr[4*q+2];
            p += hv.w * woutr[4*q+3];
        }
        p += __shfl_xor(p, 8, 64);
        p += __shfl_xor(p, 16, 64);
        p += __shfl_xor(p, 32, 64);
        float logit = (j_cls < OUT) ? (p + boutr) : -INFINITY;
        float mv = logit;
        #pragma unroll
        for (int d = 1; d < 8; d <<= 1) {
            float ov = __shfl_xor(mv, d, 64);
            if (ov > mv) mv = ov;
        }
        float e = (j_cls < OUT) ? expf(logit - mv) : 0.0f;
        float ssum = e;
        #pragma unroll
        for (int d = 1; d < 8; d <<= 1) ssum += __shfl_xor(ssum, d, 64);
        float lse = mv + logf(ssum);
        if (t < OUT) log_lds[(MAXLEN - 1) & (LOGBUF - 1)][t] = logit - lse;
    }
    __syncthreads();   // slot 255 (step 2047) ready; slots 0..254 = steps 1792..2046

    {   // final flush: steps 1792..2047
        const int base = MAXLEN - LOGBUF;
        for (int i = t; i < LOGBUF * OUT; i += NT) {
            int st = i / OUT, j = i - st * OUT;
            outlp[(size_t)(base + st) * OUT + j] = log_lds[st][j];
        }
    }

    if (t < HID) {
        out[(size_t)BATCH * MAXLEN * OUT + b * HID + t] = h_lds[t];                 // hT
        out[(size_t)BATCH * MAXLEN * OUT + BATCH * HID + b * HID + t] = c_reg;      // cT
    }
}

extern "C" void kernel_launch(void* const* d_in, const int* in_sizes, int n_in,
                              void* d_out, int out_size, void* d_ws, size_t ws_size,
                              hipStream_t stream) {
    const float* h0    = (const float*)d_in[0];
    const float* c0    = (const float*)d_in[1];
    const float* toh   = (const float*)d_in[2];
    const void*  tfm   = (const void*) d_in[3];
    const float* Wih   = (const float*)d_in[4];
    const float* Whh   = (const float*)d_in[5];
    const float* bih   = (const float*)d_in[6];
    const float* bhh   = (const float*)d_in[7];
    const float* Wout  = (const float*)d_in[8];
    const float* bout  = (const float*)d_in[9];
    float* out = (float*)d_out;

    decoder_rnn_kernel<<<dim3(BATCH), dim3(NT), 0, stream>>>(
        h0, c0, toh, tfm, Wih, Whh, bih, bhh, Wout, bout, out);
}